// Round 3
// baseline (1151.759 us; speedup 1.0000x reference)
//
#include <hip/hip_runtime.h>
#include <hip/hip_bf16.h>

#define N_GRAPH 8
#define V_NODES 4608
#define E_PER   73728
#define NV      (N_GRAPH * V_NODES)   // 36864
#define E_TOT   (N_GRAPH * E_PER)     // 589824
#define C       512
#define NCLS    3
#define LN_EPS  1e-5f
#define POOL_CHUNKS 36                // V_NODES / 128

// ---------------- helpers ----------------

__device__ inline float waveReduceSum(float v) {
#pragma unroll
    for (int o = 32; o > 0; o >>= 1) v += __shfl_down(v, o, 64);
    return v; // valid on lane 0
}

// block of 512 threads (8 waves): returns total to ALL threads
__device__ inline float blockSum512(float v, volatile float* sred) {
    float s = waveReduceSum(v);
    if ((threadIdx.x & 63) == 0) sred[threadIdx.x >> 6] = s;
    __syncthreads();
    float t = 0.f;
#pragma unroll
    for (int i = 0; i < 8; i++) t += sred[i];
    __syncthreads();
    return t;
}

// ---------------- graph preprocessing ----------------

__global__ void k_init(float* dinv, int* counts) {
    int i = blockIdx.x * 256 + threadIdx.x;
    if (i < NV) { dinv[i] = 1.0f; counts[i] = 0; }  // 1.0 = self-loop weight
}

__global__ void k_deg_count(const int* __restrict__ ei, const float* __restrict__ ew,
                            float* __restrict__ dinv, int* __restrict__ counts) {
    int e = blockIdx.x * 256 + threadIdx.x;
    if (e >= E_TOT) return;
    int off = (e / E_PER) * V_NODES;
    int t = ei[E_TOT + e] + off;
    atomicAdd(&dinv[t], ew[e]);
    atomicAdd(&counts[t], 1);
}

__global__ void k_rsqrt(float* dinv) {
    int i = blockIdx.x * 256 + threadIdx.x;
    if (i < NV) dinv[i] = rsqrtf(dinv[i]);   // deg >= 1.0 always (self loop)
}

// single-block chunked Hillis-Steele scan: counts -> row_ptr (exclusive), cursor copy
__global__ void k_scan(const int* __restrict__ counts, int* __restrict__ row_ptr,
                       int* __restrict__ cursor) {
    __shared__ int sh[1024];
    __shared__ int carry;
    if (threadIdx.x == 0) carry = 0;
    __syncthreads();
    for (int base = 0; base < NV; base += 1024) {
        int idx = base + threadIdx.x;
        int v = (idx < NV) ? counts[idx] : 0;
        sh[threadIdx.x] = v;
        __syncthreads();
#pragma unroll
        for (int off = 1; off < 1024; off <<= 1) {
            int t = (threadIdx.x >= off) ? sh[threadIdx.x - off] : 0;
            __syncthreads();
            sh[threadIdx.x] += t;
            __syncthreads();
        }
        int incl = sh[threadIdx.x];
        int excl = incl - v;
        if (idx < NV) { row_ptr[idx] = carry + excl; cursor[idx] = carry + excl; }
        __syncthreads();
        if (threadIdx.x == 1023) carry += incl;
        __syncthreads();
    }
    if (threadIdx.x == 0) row_ptr[NV] = E_TOT;
}

__global__ void k_fill(const int* __restrict__ ei, const float* __restrict__ ew,
                       const float* __restrict__ dinv, int* __restrict__ cursor,
                       int* __restrict__ col_idx, float* __restrict__ val) {
    int e = blockIdx.x * 256 + threadIdx.x;
    if (e >= E_TOT) return;
    int off = (e / E_PER) * V_NODES;
    int s = ei[e] + off;
    int t = ei[E_TOT + e] + off;
    int pos = atomicAdd(&cursor[t], 1);
    col_idx[pos] = s;
    val[pos] = dinv[s] * ew[e] * dinv[t];
}

// ---------------- layer 0: hw = x (NV x 1) outer* w0 (1 x C) ----------------

__global__ void k_layer0(const float* __restrict__ x, const float* __restrict__ w0,
                         float* __restrict__ hw) {
    size_t idx = (size_t)blockIdx.x * 256 + threadIdx.x;   // over NV*128 float4s
    int i = (int)(idx >> 7);
    int c4 = (int)(idx & 127);
    float xv = x[i];
    float4 w = reinterpret_cast<const float4*>(w0)[c4];
    float4 o = { xv * w.x, xv * w.y, xv * w.z, xv * w.w };
    reinterpret_cast<float4*>(hw)[idx] = o;
}

// ---------------- fp32 tiled GEMM: B = A[NV x C] @ W[C x C] ----------------

#define BM 64
#define BN 64
#define BK 16

__launch_bounds__(256)
__global__ void k_gemm(const float* __restrict__ A, const float* __restrict__ W,
                       float* __restrict__ Bout) {
    __shared__ float As[BK][BM];
    __shared__ float Ws[BK][BN];
    const int bm = blockIdx.x, bn = blockIdx.y;
    const int tid = threadIdx.x;
    const int tx = tid & 15, ty = tid >> 4;
    const int m0 = bm * BM, n0 = bn * BN;
    float acc[4][4] = {};
    for (int k0 = 0; k0 < C; k0 += BK) {
        {   // A tile 64x16, float4 per thread, store transposed
            int r = tid >> 2;
            int kq = (tid & 3) << 2;
            float4 a = *reinterpret_cast<const float4*>(&A[(size_t)(m0 + r) * C + k0 + kq]);
            As[kq + 0][r] = a.x; As[kq + 1][r] = a.y; As[kq + 2][r] = a.z; As[kq + 3][r] = a.w;
        }
        {   // W tile 16x64
            int kk = tid >> 4;
            int nq = (tid & 15) << 2;
            float4 w = *reinterpret_cast<const float4*>(&W[(size_t)(k0 + kk) * C + n0 + nq]);
            *reinterpret_cast<float4*>(&Ws[kk][nq]) = w;
        }
        __syncthreads();
#pragma unroll
        for (int kk = 0; kk < BK; kk++) {
            float4 a = *reinterpret_cast<const float4*>(&As[kk][ty << 2]);
            float4 b = *reinterpret_cast<const float4*>(&Ws[kk][tx << 2]);
            float av[4] = { a.x, a.y, a.z, a.w };
            float bv[4] = { b.x, b.y, b.z, b.w };
#pragma unroll
            for (int i = 0; i < 4; i++)
#pragma unroll
                for (int j = 0; j < 4; j++)
                    acc[i][j] += av[i] * bv[j];
        }
        __syncthreads();
    }
#pragma unroll
    for (int i = 0; i < 4; i++) {
        int m = m0 + (ty << 2) + i;
        float4 o = { acc[i][0], acc[i][1], acc[i][2], acc[i][3] };
        *reinterpret_cast<float4*>(&Bout[(size_t)m * C + n0 + (tx << 2)]) = o;
    }
}

// ---------------- aggregate + bias + relu + layernorm ----------------

__launch_bounds__(128)
__global__ void k_agg(const float* __restrict__ hw, const int* __restrict__ row_ptr,
                      const int* __restrict__ col_idx, const float* __restrict__ val,
                      const float* __restrict__ dinv, const float* __restrict__ bias,
                      const float* __restrict__ ln_g, const float* __restrict__ ln_b,
                      float* __restrict__ out) {
    const int t = blockIdx.x;
    const int tid = threadIdx.x;
    const int e0 = row_ptr[t], e1 = row_ptr[t + 1];
    const float4* hw4 = reinterpret_cast<const float4*>(hw);
    const float dt = dinv[t];
    float4 acc = hw4[(size_t)t * 128 + tid];
    const float selfw = dt * dt;
    acc.x *= selfw; acc.y *= selfw; acc.z *= selfw; acc.w *= selfw;

    __shared__ int   sh_s[128];
    __shared__ float sh_v[128];
    for (int base = e0; base < e1; base += 128) {
        int cnt = min(128, e1 - base);
        if (tid < cnt) { sh_s[tid] = col_idx[base + tid]; sh_v[tid] = val[base + tid]; }
        __syncthreads();
        for (int j = 0; j < cnt; j++) {
            float w = sh_v[j];
            float4 hv = hw4[(size_t)sh_s[j] * 128 + tid];
            acc.x += w * hv.x; acc.y += w * hv.y; acc.z += w * hv.z; acc.w += w * hv.w;
        }
        __syncthreads();
    }
    // bias + relu
    int c4 = tid << 2;
    float4 bb = *reinterpret_cast<const float4*>(&bias[c4]);
    acc.x = fmaxf(acc.x + bb.x, 0.f);
    acc.y = fmaxf(acc.y + bb.y, 0.f);
    acc.z = fmaxf(acc.z + bb.z, 0.f);
    acc.w = fmaxf(acc.w + bb.w, 0.f);
    // layernorm over 512 (2 waves)
    __shared__ float redA[2], redB[2];
    float s = acc.x + acc.y + acc.z + acc.w;
    float wsum = waveReduceSum(s);
    if ((tid & 63) == 0) redA[tid >> 6] = wsum;
    __syncthreads();
    float mu = (redA[0] + redA[1]) * (1.0f / C);
    float dx = acc.x - mu, dy = acc.y - mu, dz = acc.z - mu, dw = acc.w - mu;
    float sq = dx * dx + dy * dy + dz * dz + dw * dw;
    float wsq = waveReduceSum(sq);
    if ((tid & 63) == 0) redB[tid >> 6] = wsq;
    __syncthreads();
    float var = (redB[0] + redB[1]) * (1.0f / C);
    float rstd = rsqrtf(var + LN_EPS);
    float4 g = *reinterpret_cast<const float4*>(&ln_g[c4]);
    float4 b = *reinterpret_cast<const float4*>(&ln_b[c4]);
    float4 o = { dx * rstd * g.x + b.x, dy * rstd * g.y + b.y,
                 dz * rstd * g.z + b.z, dw * rstd * g.w + b.w };
    reinterpret_cast<float4*>(out)[(size_t)t * 128 + tid] = o;
}

// ---------------- pooling + final LN + head ----------------

__global__ void k_pool1(const float* __restrict__ h, float* __restrict__ pmax) {
    int g = blockIdx.x, chunk = blockIdx.y;
    int c = threadIdx.x;  // 512
    int r0 = g * V_NODES + chunk * 128;
    float m = -1e30f;
#pragma unroll 4
    for (int r = 0; r < 128; r++)
        m = fmaxf(m, h[(size_t)(r0 + r) * C + c]);
    pmax[((size_t)g * POOL_CHUNKS + chunk) * C + c] = m;
}

__global__ void k_pool2_head(const float* __restrict__ pmax, const float* __restrict__ ln_g,
                             const float* __restrict__ ln_b, const float* __restrict__ hw,
                             const float* __restrict__ hb, float* __restrict__ out) {
    __shared__ float sred[8];
    int g = blockIdx.x;
    int c = threadIdx.x;  // 512
    float m = -1e30f;
#pragma unroll
    for (int j = 0; j < POOL_CHUNKS; j++)
        m = fmaxf(m, pmax[((size_t)g * POOL_CHUNKS + j) * C + c]);
    float total = blockSum512(m, sred);
    float mu = total * (1.0f / C);
    float d = m - mu;
    float var = blockSum512(d * d, sred) * (1.0f / C);
    float rstd = rsqrtf(var + LN_EPS);
    float p = d * rstd * ln_g[c] + ln_b[c];
    float r0 = blockSum512(p * hw[c * NCLS + 0], sred);
    float r1 = blockSum512(p * hw[c * NCLS + 1], sred);
    float r2 = blockSum512(p * hw[c * NCLS + 2], sred);
    if (threadIdx.x == 0) {
        out[g * NCLS + 0] = r0 + hb[0];
        out[g * NCLS + 1] = r1 + hb[1];
        out[g * NCLS + 2] = r2 + hb[2];
    }
}

// ---------------- launch ----------------

extern "C" void kernel_launch(void* const* d_in, const int* in_sizes, int n_in,
                              void* d_out, int out_size, void* d_ws, size_t ws_size,
                              hipStream_t stream) {
    const float* x      = (const float*)d_in[0];
    const float* ew     = (const float*)d_in[1];
    const float* w0     = (const float*)d_in[2];
    const float* b0     = (const float*)d_in[3];
    const float* w1     = (const float*)d_in[4];
    const float* b1     = (const float*)d_in[5];
    const float* w2     = (const float*)d_in[6];
    const float* b2     = (const float*)d_in[7];
    const float* ln_g   = (const float*)d_in[8];
    const float* ln_b   = (const float*)d_in[9];
    const float* head_w = (const float*)d_in[10];
    const float* head_b = (const float*)d_in[11];
    const int*   ei     = (const int*)d_in[12];
    float* out = (float*)d_out;

    char* p = (char*)d_ws;
    auto alloc = [&](size_t bytes) { void* r = p; p += (bytes + 255) & ~255ull; return r; };
    float* bufA    = (float*)alloc((size_t)NV * C * 4);
    float* bufB    = (float*)alloc((size_t)NV * C * 4);
    float* dinv    = (float*)alloc((size_t)NV * 4);
    int*   counts  = (int*)alloc((size_t)NV * 4);
    int*   row_ptr = (int*)alloc((size_t)(NV + 1) * 4);
    int*   cursor  = (int*)alloc((size_t)NV * 4);
    int*   col_idx = (int*)alloc((size_t)E_TOT * 4);
    float* val     = (float*)alloc((size_t)E_TOT * 4);
    float* pmax    = (float*)alloc((size_t)N_GRAPH * POOL_CHUNKS * C * 4);

    // graph preprocessing
    k_init<<<NV / 256, 256, 0, stream>>>(dinv, counts);
    k_deg_count<<<E_TOT / 256, 256, 0, stream>>>(ei, ew, dinv, counts);
    k_rsqrt<<<NV / 256, 256, 0, stream>>>(dinv);
    k_scan<<<1, 1024, 0, stream>>>(counts, row_ptr, cursor);
    k_fill<<<E_TOT / 256, 256, 0, stream>>>(ei, ew, dinv, cursor, col_idx, val);

    // layer 0
    k_layer0<<<(NV * 128) / 256, 256, 0, stream>>>(x, w0, bufB);
    k_agg<<<NV, 128, 0, stream>>>(bufB, row_ptr, col_idx, val, dinv, b0, ln_g, ln_b, bufA);

    // layer 1
    k_gemm<<<dim3(NV / BM, C / BN), 256, 0, stream>>>(bufA, w1, bufB);
    k_agg<<<NV, 128, 0, stream>>>(bufB, row_ptr, col_idx, val, dinv, b1, ln_g, ln_b, bufA);

    // layer 2
    k_gemm<<<dim3(NV / BM, C / BN), 256, 0, stream>>>(bufA, w2, bufB);
    k_agg<<<NV, 128, 0, stream>>>(bufB, row_ptr, col_idx, val, dinv, b2, ln_g, ln_b, bufA);

    // pooling + head
    k_pool1<<<dim3(N_GRAPH, POOL_CHUNKS), C, 0, stream>>>(bufA, pmax);
    k_pool2_head<<<N_GRAPH, C, 0, stream>>>(pmax, ln_g, ln_b, head_w, head_b, out);
}

// Round 6
// 527.236 us; speedup vs baseline: 2.1845x; 2.1845x over previous
//
#include <hip/hip_runtime.h>
#include <hip/hip_bf16.h>
#include <stdint.h>

#define N_GRAPH 8
#define V_NODES 4608
#define E_PER   73728
#define NV      (N_GRAPH * V_NODES)   // 36864
#define E_TOT   (N_GRAPH * E_PER)     // 589824
#define C       512
#define NCLS    3
#define LN_EPS  1e-5f
#define POOL_CHUNKS 36                // V_NODES / 128

typedef __attribute__((ext_vector_type(8))) short short8;
typedef __attribute__((ext_vector_type(4))) float floatx4;
typedef __attribute__((address_space(1))) void v_g;
typedef __attribute__((address_space(3))) void v_l;

// ---------------- helpers ----------------

__device__ inline float waveReduceSum(float v) {
#pragma unroll
    for (int o = 32; o > 0; o >>= 1) v += __shfl_down(v, o, 64);
    return v; // valid on lane 0
}

__device__ inline float blockSum512(float v, volatile float* sred) {
    float s = waveReduceSum(v);
    if ((threadIdx.x & 63) == 0) sred[threadIdx.x >> 6] = s;
    __syncthreads();
    float t = 0.f;
#pragma unroll
    for (int i = 0; i < 8; i++) t += sred[i];
    __syncthreads();
    return t;
}

__device__ inline unsigned short f2bf(float f) {   // RNE
    uint32_t u = __float_as_uint(f);
    u += 0x7fffu + ((u >> 16) & 1u);
    return (unsigned short)(u >> 16);
}
__device__ inline float bf2f(unsigned short b) {
    return __uint_as_float(((uint32_t)b) << 16);
}

// ---------------- graph preprocessing ----------------

__global__ void k_init(float* dinv, int* counts) {
    int i = blockIdx.x * 256 + threadIdx.x;
    if (i < NV) { dinv[i] = 1.0f; counts[i] = 0; }  // 1.0 = self-loop weight
}

__global__ void k_deg_count(const int* __restrict__ ei, const float* __restrict__ ew,
                            float* __restrict__ dinv, int* __restrict__ counts) {
    int e = blockIdx.x * 256 + threadIdx.x;
    if (e >= E_TOT) return;
    int off = (e / E_PER) * V_NODES;
    int t = ei[E_TOT + e] + off;
    atomicAdd(&dinv[t], ew[e]);
    atomicAdd(&counts[t], 1);
}

__global__ void k_rsqrt(float* dinv) {
    int i = blockIdx.x * 256 + threadIdx.x;
    if (i < NV) dinv[i] = rsqrtf(dinv[i]);
}

__global__ void k_scan(const int* __restrict__ counts, int* __restrict__ row_ptr,
                       int* __restrict__ cursor) {
    __shared__ int sh[1024];
    __shared__ int carry;
    if (threadIdx.x == 0) carry = 0;
    __syncthreads();
    for (int base = 0; base < NV; base += 1024) {
        int idx = base + threadIdx.x;
        int v = (idx < NV) ? counts[idx] : 0;
        sh[threadIdx.x] = v;
        __syncthreads();
#pragma unroll
        for (int off = 1; off < 1024; off <<= 1) {
            int t = (threadIdx.x >= off) ? sh[threadIdx.x - off] : 0;
            __syncthreads();
            sh[threadIdx.x] += t;
            __syncthreads();
        }
        int incl = sh[threadIdx.x];
        int excl = incl - v;
        if (idx < NV) { row_ptr[idx] = carry + excl; cursor[idx] = carry + excl; }
        __syncthreads();
        if (threadIdx.x == 1023) carry += incl;
        __syncthreads();
    }
    if (threadIdx.x == 0) row_ptr[NV] = E_TOT;
}

__global__ void k_fill(const int* __restrict__ ei, const float* __restrict__ ew,
                       const float* __restrict__ dinv, int* __restrict__ cursor,
                       int* __restrict__ col_idx, float* __restrict__ val) {
    int e = blockIdx.x * 256 + threadIdx.x;
    if (e >= E_TOT) return;
    int off = (e / E_PER) * V_NODES;
    int s = ei[e] + off;
    int t = ei[E_TOT + e] + off;
    int pos = atomicAdd(&cursor[t], 1);
    col_idx[pos] = s;
    val[pos] = dinv[s] * ew[e] * dinv[t];
}

// ---------------- weight convert: WT[n][k] = bf16(W[k][n]) for w1,w2 ------

__global__ void k_wt(const float* __restrict__ w1, const float* __restrict__ w2,
                     unsigned short* __restrict__ wt1, unsigned short* __restrict__ wt2) {
    int idx = blockIdx.x * 256 + threadIdx.x;     // 0 .. 2*512*512-1
    int which = idx >> 18;
    int rem = idx & 0x3ffff;
    int n = rem >> 9, k = rem & 511;
    const float* W = which ? w2 : w1;
    unsigned short* WT = which ? wt2 : wt1;
    WT[n * C + k] = f2bf(W[k * C + n]);
}

// ---------------- layer 0 (D_IN=1 collapse): scalar agg then expand -------

__global__ void k_agg0_scalar(const float* __restrict__ x, const int* __restrict__ row_ptr,
                              const int* __restrict__ col_idx, const float* __restrict__ val,
                              const float* __restrict__ dinv, float* __restrict__ s0) {
    int t = blockIdx.x * 256 + threadIdx.x;
    if (t >= NV) return;
    float dt = dinv[t];
    float acc = dt * dt * x[t];
    int e1 = row_ptr[t + 1];
    for (int e = row_ptr[t]; e < e1; e++)
        acc += val[e] * x[col_idx[e]];
    s0[t] = acc;
}

// h0 = bf16( LN( relu(s0*w0 + b0) ) )  — one block (128 thr) per node
__launch_bounds__(128)
__global__ void k_l0post(const float* __restrict__ s0, const float* __restrict__ w0,
                         const float* __restrict__ b0, const float* __restrict__ ln_g,
                         const float* __restrict__ ln_b, unsigned short* __restrict__ out) {
    const int t = blockIdx.x;
    const int tid = threadIdx.x;
    const int c4 = tid << 2;
    float s = s0[t];
    float4 w = *reinterpret_cast<const float4*>(&w0[c4]);
    float4 bb = *reinterpret_cast<const float4*>(&b0[c4]);
    float vx = fmaxf(s * w.x + bb.x, 0.f);
    float vy = fmaxf(s * w.y + bb.y, 0.f);
    float vz = fmaxf(s * w.z + bb.z, 0.f);
    float vw = fmaxf(s * w.w + bb.w, 0.f);
    __shared__ float redA[2], redB[2];
    float wsum = waveReduceSum(vx + vy + vz + vw);
    if ((tid & 63) == 0) redA[tid >> 6] = wsum;
    __syncthreads();
    float mu = (redA[0] + redA[1]) * (1.0f / C);
    float dx = vx - mu, dy = vy - mu, dz = vz - mu, dw = vw - mu;
    float wsq = waveReduceSum(dx * dx + dy * dy + dz * dz + dw * dw);
    if ((tid & 63) == 0) redB[tid >> 6] = wsq;
    __syncthreads();
    float rstd = rsqrtf((redB[0] + redB[1]) * (1.0f / C) + LN_EPS);
    float4 g = *reinterpret_cast<const float4*>(&ln_g[c4]);
    float4 b = *reinterpret_cast<const float4*>(&ln_b[c4]);
    ushort4 o = { f2bf(dx * rstd * g.x + b.x), f2bf(dy * rstd * g.y + b.y),
                  f2bf(dz * rstd * g.z + b.z), f2bf(dw * rstd * g.w + b.w) };
    reinterpret_cast<ushort4*>(out)[(size_t)t * 128 + tid] = o;
}

// ---------------- bf16 MFMA GEMM: Bout[M,N] = A[M,K] @ WT[N,K]^T ----------
// 128x128 tile, 4 waves (2x2 of 64x64), 16x16x32 MFMA, BK=32.
// LDS layout: [kg:4][idx:128] of 16B (8 bf16) — staged linearly by global_load_lds.

__launch_bounds__(256)
__global__ void k_gemm_mfma(const unsigned short* __restrict__ A,
                            const unsigned short* __restrict__ WT,
                            unsigned short* __restrict__ Bout) {
    __shared__ short8 lA[512];
    __shared__ short8 lB[512];
    const int tid = threadIdx.x;
    const int lane = tid & 63;
    const int wave = tid >> 6;
    const int wr = wave >> 1, wc = wave & 1;
    const int l15 = lane & 15, kg = lane >> 4;
    const int n0 = blockIdx.x * 128;      // x = N block (4) -> A-panel reuse adjacency
    const int m0 = blockIdx.y * 128;      // y = M block (288)

    floatx4 acc[4][4] = {};

    // staging: slot s = i*256 + tid, s -> (kgs = s>>7, idx = s&127)
    const int s0i = tid, s1i = 256 + tid;
    const int kgs0 = s0i >> 7, idx0 = s0i & 127;
    const int kgs1 = s1i >> 7, idx1 = s1i & 127;
    const unsigned short* gA0 = A + (size_t)(m0 + idx0) * C + kgs0 * 8;
    const unsigned short* gA1 = A + (size_t)(m0 + idx1) * C + kgs1 * 8;
    const unsigned short* gB0 = WT + (size_t)(n0 + idx0) * C + kgs0 * 8;
    const unsigned short* gB1 = WT + (size_t)(n0 + idx1) * C + kgs1 * 8;

    for (int k0 = 0; k0 < C; k0 += 32) {
        __builtin_amdgcn_global_load_lds((v_g*)(gA0 + k0), (v_l*)&lA[s0i], 16, 0, 0);
        __builtin_amdgcn_global_load_lds((v_g*)(gA1 + k0), (v_l*)&lA[s1i], 16, 0, 0);
        __builtin_amdgcn_global_load_lds((v_g*)(gB0 + k0), (v_l*)&lB[s0i], 16, 0, 0);
        __builtin_amdgcn_global_load_lds((v_g*)(gB1 + k0), (v_l*)&lB[s1i], 16, 0, 0);
        asm volatile("s_waitcnt vmcnt(0)" ::: "memory");
        __syncthreads();

        short8 af[4], bf[4];
#pragma unroll
        for (int mi = 0; mi < 4; mi++)
            af[mi] = lA[kg * 128 + wr * 64 + mi * 16 + l15];
#pragma unroll
        for (int ni = 0; ni < 4; ni++)
            bf[ni] = lB[kg * 128 + wc * 64 + ni * 16 + l15];
#pragma unroll
        for (int mi = 0; mi < 4; mi++)
#pragma unroll
            for (int ni = 0; ni < 4; ni++)
                acc[mi][ni] = __builtin_amdgcn_mfma_f32_16x16x32_bf16(
                    af[mi], bf[ni], acc[mi][ni], 0, 0, 0);
        __syncthreads();
    }

    // D layout: col = lane&15, row = (lane>>4)*4 + reg   [m89-verified]
#pragma unroll
    for (int mi = 0; mi < 4; mi++) {
#pragma unroll
        for (int ni = 0; ni < 4; ni++) {
            int n = n0 + wc * 64 + ni * 16 + l15;
#pragma unroll
            for (int r = 0; r < 4; r++) {
                int m = m0 + wr * 64 + mi * 16 + kg * 4 + r;
                Bout[(size_t)m * C + n] = f2bf(acc[mi][ni][r]);
            }
        }
    }
}

// ---------------- aggregate (bf16 gather) + bias + relu + LN --------------

__launch_bounds__(128)
__global__ void k_agg(const unsigned short* __restrict__ hw, const int* __restrict__ row_ptr,
                      const int* __restrict__ col_idx, const float* __restrict__ val,
                      const float* __restrict__ dinv, const float* __restrict__ bias,
                      const float* __restrict__ ln_g, const float* __restrict__ ln_b,
                      unsigned short* __restrict__ out) {
    const int t = blockIdx.x;
    const int tid = threadIdx.x;
    const int e0 = row_ptr[t], e1 = row_ptr[t + 1];
    const ushort4* hw4 = reinterpret_cast<const ushort4*>(hw);
    const float dt = dinv[t];
    const float selfw = dt * dt;
    ushort4 hs = hw4[(size_t)t * 128 + tid];
    float ax = selfw * bf2f(hs.x), ay = selfw * bf2f(hs.y);
    float az = selfw * bf2f(hs.z), aw = selfw * bf2f(hs.w);

    __shared__ int   sh_s[128];
    __shared__ float sh_v[128];
    for (int base = e0; base < e1; base += 128) {
        int cnt = min(128, e1 - base);
        if (tid < cnt) { sh_s[tid] = col_idx[base + tid]; sh_v[tid] = val[base + tid]; }
        __syncthreads();
        for (int j = 0; j < cnt; j++) {
            float w = sh_v[j];
            ushort4 hv = hw4[(size_t)sh_s[j] * 128 + tid];
            ax += w * bf2f(hv.x); ay += w * bf2f(hv.y);
            az += w * bf2f(hv.z); aw += w * bf2f(hv.w);
        }
        __syncthreads();
    }
    int c4 = tid << 2;
    float4 bb = *reinterpret_cast<const float4*>(&bias[c4]);
    ax = fmaxf(ax + bb.x, 0.f); ay = fmaxf(ay + bb.y, 0.f);
    az = fmaxf(az + bb.z, 0.f); aw = fmaxf(aw + bb.w, 0.f);
    __shared__ float redA[2], redB[2];
    float wsum = waveReduceSum(ax + ay + az + aw);
    if ((tid & 63) == 0) redA[tid >> 6] = wsum;
    __syncthreads();
    float mu = (redA[0] + redA[1]) * (1.0f / C);
    float dx = ax - mu, dy = ay - mu, dz = az - mu, dw = aw - mu;
    float wsq = waveReduceSum(dx * dx + dy * dy + dz * dz + dw * dw);
    if ((tid & 63) == 0) redB[tid >> 6] = wsq;
    __syncthreads();
    float rstd = rsqrtf((redB[0] + redB[1]) * (1.0f / C) + LN_EPS);
    float4 g = *reinterpret_cast<const float4*>(&ln_g[c4]);
    float4 b = *reinterpret_cast<const float4*>(&ln_b[c4]);
    ushort4 o = { f2bf(dx * rstd * g.x + b.x), f2bf(dy * rstd * g.y + b.y),
                  f2bf(dz * rstd * g.z + b.z), f2bf(dw * rstd * g.w + b.w) };
    reinterpret_cast<ushort4*>(out)[(size_t)t * 128 + tid] = o;
}

// ---------------- pooling + final LN + head ----------------

__global__ void k_pool1(const unsigned short* __restrict__ h, float* __restrict__ pmax) {
    int g = blockIdx.x, chunk = blockIdx.y;
    int c = threadIdx.x;  // 512
    int r0 = g * V_NODES + chunk * 128;
    float m = -1e30f;
#pragma unroll 4
    for (int r = 0; r < 128; r++)
        m = fmaxf(m, bf2f(h[(size_t)(r0 + r) * C + c]));
    pmax[((size_t)g * POOL_CHUNKS + chunk) * C + c] = m;
}

__global__ void k_pool2_head(const float* __restrict__ pmax, const float* __restrict__ ln_g,
                             const float* __restrict__ ln_b, const float* __restrict__ hw,
                             const float* __restrict__ hb, float* __restrict__ out) {
    __shared__ float sred[8];
    int g = blockIdx.x;
    int c = threadIdx.x;  // 512
    float m = -1e30f;
#pragma unroll
    for (int j = 0; j < POOL_CHUNKS; j++)
        m = fmaxf(m, pmax[((size_t)g * POOL_CHUNKS + j) * C + c]);
    float total = blockSum512(m, sred);
    float mu = total * (1.0f / C);
    float d = m - mu;
    float var = blockSum512(d * d, sred) * (1.0f / C);
    float rstd = rsqrtf(var + LN_EPS);
    float p = d * rstd * ln_g[c] + ln_b[c];
    float r0 = blockSum512(p * hw[c * NCLS + 0], sred);
    float r1 = blockSum512(p * hw[c * NCLS + 1], sred);
    float r2 = blockSum512(p * hw[c * NCLS + 2], sred);
    if (threadIdx.x == 0) {
        out[g * NCLS + 0] = r0 + hb[0];
        out[g * NCLS + 1] = r1 + hb[1];
        out[g * NCLS + 2] = r2 + hb[2];
    }
}

// ---------------- launch ----------------

extern "C" void kernel_launch(void* const* d_in, const int* in_sizes, int n_in,
                              void* d_out, int out_size, void* d_ws, size_t ws_size,
                              hipStream_t stream) {
    const float* x      = (const float*)d_in[0];
    const float* ew     = (const float*)d_in[1];
    const float* w0     = (const float*)d_in[2];
    const float* b0     = (const float*)d_in[3];
    const float* w1     = (const float*)d_in[4];
    const float* b1     = (const float*)d_in[5];
    const float* w2     = (const float*)d_in[6];
    const float* b2     = (const float*)d_in[7];
    const float* ln_g   = (const float*)d_in[8];
    const float* ln_b   = (const float*)d_in[9];
    const float* head_w = (const float*)d_in[10];
    const float* head_b = (const float*)d_in[11];
    const int*   ei     = (const int*)d_in[12];
    float* out = (float*)d_out;

    char* p = (char*)d_ws;
    auto alloc = [&](size_t bytes) { void* r = p; p += (bytes + 255) & ~255ull; return r; };
    unsigned short* bufA = (unsigned short*)alloc((size_t)NV * C * 2);
    unsigned short* bufB = (unsigned short*)alloc((size_t)NV * C * 2);
    unsigned short* wt1  = (unsigned short*)alloc((size_t)C * C * 2);
    unsigned short* wt2  = (unsigned short*)alloc((size_t)C * C * 2);
    float* s0      = (float*)alloc((size_t)NV * 4);
    float* dinv    = (float*)alloc((size_t)NV * 4);
    int*   counts  = (int*)alloc((size_t)NV * 4);
    int*   row_ptr = (int*)alloc((size_t)(NV + 1) * 4);
    int*   cursor  = (int*)alloc((size_t)NV * 4);
    int*   col_idx = (int*)alloc((size_t)E_TOT * 4);
    float* val     = (float*)alloc((size_t)E_TOT * 4);
    float* pmax    = (float*)alloc((size_t)N_GRAPH * POOL_CHUNKS * C * 4);

    // graph preprocessing
    k_init<<<NV / 256, 256, 0, stream>>>(dinv, counts);
    k_deg_count<<<E_TOT / 256, 256, 0, stream>>>(ei, ew, dinv, counts);
    k_rsqrt<<<NV / 256, 256, 0, stream>>>(dinv);
    k_scan<<<1, 1024, 0, stream>>>(counts, row_ptr, cursor);
    k_fill<<<E_TOT / 256, 256, 0, stream>>>(ei, ew, dinv, cursor, col_idx, val);
    k_wt<<<(2 * C * C) / 256, 256, 0, stream>>>(w1, w2, wt1, wt2);

    // layer 0 (collapsed: scalar agg, then expand+LN)
    k_agg0_scalar<<<NV / 256, 256, 0, stream>>>(x, row_ptr, col_idx, val, dinv, s0);
    k_l0post<<<NV, 128, 0, stream>>>(s0, w0, b0, ln_g, ln_b, bufA);

    // layer 1
    k_gemm_mfma<<<dim3(C / 128, NV / 128), 256, 0, stream>>>(bufA, wt1, bufB);
    k_agg<<<NV, 128, 0, stream>>>(bufB, row_ptr, col_idx, val, dinv, b1, ln_g, ln_b, bufA);

    // layer 2
    k_gemm_mfma<<<dim3(C / 128, NV / 128), 256, 0, stream>>>(bufA, wt2, bufB);
    k_agg<<<NV, 128, 0, stream>>>(bufB, row_ptr, col_idx, val, dinv, b2, ln_g, ln_b, bufA);

    // pooling + head
    k_pool1<<<dim3(N_GRAPH, POOL_CHUNKS), C, 0, stream>>>(bufA, pmax);
    k_pool2_head<<<N_GRAPH, C, 0, stream>>>(pmax, ln_g, ln_b, head_w, head_b, out);
}

// Round 7
// 468.826 us; speedup vs baseline: 2.4567x; 1.1246x over previous
//
#include <hip/hip_runtime.h>
#include <hip/hip_bf16.h>
#include <stdint.h>

#define N_GRAPH 8
#define V_NODES 4608
#define E_PER   73728
#define NV      (N_GRAPH * V_NODES)   // 36864
#define E_TOT   (N_GRAPH * E_PER)     // 589824
#define C       512
#define NCLS    3
#define LN_EPS  1e-5f
#define POOL_CHUNKS 36                // V_NODES / 128
#define SCAN_BLOCKS 144               // NV / 256

typedef __attribute__((ext_vector_type(8))) short short8;
typedef __attribute__((ext_vector_type(4))) float floatx4;
typedef __attribute__((address_space(1))) void v_g;
typedef __attribute__((address_space(3))) void v_l;

// ---------------- helpers ----------------

__device__ inline float waveReduceSum(float v) {
#pragma unroll
    for (int o = 32; o > 0; o >>= 1) v += __shfl_down(v, o, 64);
    return v; // valid on lane 0
}

__device__ inline float blockSum512(float v, volatile float* sred) {
    float s = waveReduceSum(v);
    if ((threadIdx.x & 63) == 0) sred[threadIdx.x >> 6] = s;
    __syncthreads();
    float t = 0.f;
#pragma unroll
    for (int i = 0; i < 8; i++) t += sred[i];
    __syncthreads();
    return t;
}

__device__ inline unsigned short f2bf(float f) {   // RNE
    uint32_t u = __float_as_uint(f);
    u += 0x7fffu + ((u >> 16) & 1u);
    return (unsigned short)(u >> 16);
}
__device__ inline float bf2f(unsigned short b) {
    return __uint_as_float(((uint32_t)b) << 16);
}

// ---------------- graph preprocessing ----------------

__global__ void k_init(float* dinv, int* counts) {
    int i = blockIdx.x * 256 + threadIdx.x;
    if (i < NV) { dinv[i] = 1.0f; counts[i] = 0; }  // 1.0 = self-loop weight
}

__global__ void k_deg_count(const int* __restrict__ ei, const float* __restrict__ ew,
                            float* __restrict__ dinv, int* __restrict__ counts) {
    int e = blockIdx.x * 256 + threadIdx.x;
    if (e >= E_TOT) return;
    int off = (e / E_PER) * V_NODES;
    int t = ei[E_TOT + e] + off;
    atomicAdd(&dinv[t], ew[e]);
    atomicAdd(&counts[t], 1);
}

__global__ void k_rsqrt(float* dinv) {
    int i = blockIdx.x * 256 + threadIdx.x;
    if (i < NV) dinv[i] = rsqrtf(dinv[i]);
}

// ---- multi-block exclusive scan of counts -> row_ptr (3 small kernels) ----

__global__ void k_scan1(const int* __restrict__ counts, int* __restrict__ row_ptr,
                        int* __restrict__ bsum) {
    __shared__ int sh[256];
    const int b = blockIdx.x, tid = threadIdx.x;
    const int idx = b * 256 + tid;
    int v = counts[idx];
    sh[tid] = v;
    __syncthreads();
#pragma unroll
    for (int off = 1; off < 256; off <<= 1) {
        int t = (tid >= off) ? sh[tid - off] : 0;
        __syncthreads();
        sh[tid] += t;
        __syncthreads();
    }
    row_ptr[idx] = sh[tid] - v;            // exclusive within block
    if (tid == 255) bsum[b] = sh[255];     // block total
}

__global__ void k_scan2(int* __restrict__ bsum) {   // 1 block, 256 threads
    __shared__ int sh[256];
    const int tid = threadIdx.x;
    int v = (tid < SCAN_BLOCKS) ? bsum[tid] : 0;
    sh[tid] = v;
    __syncthreads();
#pragma unroll
    for (int off = 1; off < 256; off <<= 1) {
        int t = (tid >= off) ? sh[tid - off] : 0;
        __syncthreads();
        sh[tid] += t;
        __syncthreads();
    }
    if (tid < SCAN_BLOCKS) bsum[tid] = sh[tid] - v;  // exclusive block offsets
}

__global__ void k_scan3(int* __restrict__ row_ptr, const int* __restrict__ bsum,
                        int* __restrict__ cursor) {
    const int b = blockIdx.x, tid = threadIdx.x;
    const int idx = b * 256 + tid;
    int v = row_ptr[idx] + bsum[b];
    row_ptr[idx] = v;
    cursor[idx] = v;
    if (idx == 0) row_ptr[NV] = E_TOT;
}

__global__ void k_fill(const int* __restrict__ ei, const float* __restrict__ ew,
                       const float* __restrict__ dinv, int* __restrict__ cursor,
                       int* __restrict__ col_idx, float* __restrict__ val) {
    int e = blockIdx.x * 256 + threadIdx.x;
    if (e >= E_TOT) return;
    int off = (e / E_PER) * V_NODES;
    int s = ei[e] + off;
    int t = ei[E_TOT + e] + off;
    int pos = atomicAdd(&cursor[t], 1);
    col_idx[pos] = s;
    val[pos] = dinv[s] * ew[e] * dinv[t];
}

// ---------------- weight convert: WT[n][k] = bf16(W[k][n]) for w1,w2 ------

__global__ void k_wt(const float* __restrict__ w1, const float* __restrict__ w2,
                     unsigned short* __restrict__ wt1, unsigned short* __restrict__ wt2) {
    int idx = blockIdx.x * 256 + threadIdx.x;     // 0 .. 2*512*512-1
    int which = idx >> 18;
    int rem = idx & 0x3ffff;
    int n = rem >> 9, k = rem & 511;
    const float* W = which ? w2 : w1;
    unsigned short* WT = which ? wt2 : wt1;
    WT[n * C + k] = f2bf(W[k * C + n]);
}

// ---------------- layer 0 (D_IN=1 collapse): scalar agg then expand -------

__global__ void k_agg0_scalar(const float* __restrict__ x, const int* __restrict__ row_ptr,
                              const int* __restrict__ col_idx, const float* __restrict__ val,
                              const float* __restrict__ dinv, float* __restrict__ s0) {
    int t = blockIdx.x * 256 + threadIdx.x;
    if (t >= NV) return;
    float dt = dinv[t];
    float acc = dt * dt * x[t];
    int e1 = row_ptr[t + 1];
    for (int e = row_ptr[t]; e < e1; e++)
        acc += val[e] * x[col_idx[e]];
    s0[t] = acc;
}

// h0 = bf16( LN( relu(s0*w0 + b0) ) )  — one block (128 thr) per node
__launch_bounds__(128)
__global__ void k_l0post(const float* __restrict__ s0, const float* __restrict__ w0,
                         const float* __restrict__ b0, const float* __restrict__ ln_g,
                         const float* __restrict__ ln_b, unsigned short* __restrict__ out) {
    const int t = blockIdx.x;
    const int tid = threadIdx.x;
    const int c4 = tid << 2;
    float s = s0[t];
    float4 w = *reinterpret_cast<const float4*>(&w0[c4]);
    float4 bb = *reinterpret_cast<const float4*>(&b0[c4]);
    float vx = fmaxf(s * w.x + bb.x, 0.f);
    float vy = fmaxf(s * w.y + bb.y, 0.f);
    float vz = fmaxf(s * w.z + bb.z, 0.f);
    float vw = fmaxf(s * w.w + bb.w, 0.f);
    __shared__ float redA[2], redB[2];
    float wsum = waveReduceSum(vx + vy + vz + vw);
    if ((tid & 63) == 0) redA[tid >> 6] = wsum;
    __syncthreads();
    float mu = (redA[0] + redA[1]) * (1.0f / C);
    float dx = vx - mu, dy = vy - mu, dz = vz - mu, dw = vw - mu;
    float wsq = waveReduceSum(dx * dx + dy * dy + dz * dz + dw * dw);
    if ((tid & 63) == 0) redB[tid >> 6] = wsq;
    __syncthreads();
    float rstd = rsqrtf((redB[0] + redB[1]) * (1.0f / C) + LN_EPS);
    float4 g = *reinterpret_cast<const float4*>(&ln_g[c4]);
    float4 b = *reinterpret_cast<const float4*>(&ln_b[c4]);
    ushort4 o = { f2bf(dx * rstd * g.x + b.x), f2bf(dy * rstd * g.y + b.y),
                  f2bf(dz * rstd * g.z + b.z), f2bf(dw * rstd * g.w + b.w) };
    reinterpret_cast<ushort4*>(out)[(size_t)t * 128 + tid] = o;
}

// ---------------- bf16 MFMA GEMM: Bout[M,N] = A[M,K] @ WT[N,K]^T ----------
// 128x128 tile, 4 waves (2x2 of 64x64), 16x16x32 MFMA, BK=32.
// LDS layout: [kg:4][idx:128] of 16B (8 bf16) — staged linearly by global_load_lds.

__launch_bounds__(256)
__global__ void k_gemm_mfma(const unsigned short* __restrict__ A,
                            const unsigned short* __restrict__ WT,
                            unsigned short* __restrict__ Bout) {
    __shared__ short8 lA[512];
    __shared__ short8 lB[512];
    const int tid = threadIdx.x;
    const int lane = tid & 63;
    const int wave = tid >> 6;
    const int wr = wave >> 1, wc = wave & 1;
    const int l15 = lane & 15, kg = lane >> 4;
    const int n0 = blockIdx.x * 128;      // x = N block (4) -> A-panel reuse adjacency
    const int m0 = blockIdx.y * 128;      // y = M block (288)

    floatx4 acc[4][4] = {};

    // staging: slot s = i*256 + tid, s -> (kgs = s>>7, idx = s&127)
    const int s0i = tid, s1i = 256 + tid;
    const int kgs0 = s0i >> 7, idx0 = s0i & 127;
    const int kgs1 = s1i >> 7, idx1 = s1i & 127;
    const unsigned short* gA0 = A + (size_t)(m0 + idx0) * C + kgs0 * 8;
    const unsigned short* gA1 = A + (size_t)(m0 + idx1) * C + kgs1 * 8;
    const unsigned short* gB0 = WT + (size_t)(n0 + idx0) * C + kgs0 * 8;
    const unsigned short* gB1 = WT + (size_t)(n0 + idx1) * C + kgs1 * 8;

    for (int k0 = 0; k0 < C; k0 += 32) {
        __builtin_amdgcn_global_load_lds((v_g*)(gA0 + k0), (v_l*)&lA[s0i], 16, 0, 0);
        __builtin_amdgcn_global_load_lds((v_g*)(gA1 + k0), (v_l*)&lA[s1i], 16, 0, 0);
        __builtin_amdgcn_global_load_lds((v_g*)(gB0 + k0), (v_l*)&lB[s0i], 16, 0, 0);
        __builtin_amdgcn_global_load_lds((v_g*)(gB1 + k0), (v_l*)&lB[s1i], 16, 0, 0);
        asm volatile("s_waitcnt vmcnt(0)" ::: "memory");
        __syncthreads();

        short8 af[4], bf[4];
#pragma unroll
        for (int mi = 0; mi < 4; mi++)
            af[mi] = lA[kg * 128 + wr * 64 + mi * 16 + l15];
#pragma unroll
        for (int ni = 0; ni < 4; ni++)
            bf[ni] = lB[kg * 128 + wc * 64 + ni * 16 + l15];
#pragma unroll
        for (int mi = 0; mi < 4; mi++)
#pragma unroll
            for (int ni = 0; ni < 4; ni++)
                acc[mi][ni] = __builtin_amdgcn_mfma_f32_16x16x32_bf16(
                    af[mi], bf[ni], acc[mi][ni], 0, 0, 0);
        __syncthreads();
    }

    // D layout: col = lane&15, row = (lane>>4)*4 + reg   [m89-verified]
#pragma unroll
    for (int mi = 0; mi < 4; mi++) {
#pragma unroll
        for (int ni = 0; ni < 4; ni++) {
            int n = n0 + wc * 64 + ni * 16 + l15;
#pragma unroll
            for (int r = 0; r < 4; r++) {
                int m = m0 + wr * 64 + mi * 16 + kg * 4 + r;
                Bout[(size_t)m * C + n] = f2bf(acc[mi][ni][r]);
            }
        }
    }
}

// ---------------- aggregate (bf16 gather) + bias + relu + LN --------------

__launch_bounds__(128)
__global__ void k_agg(const unsigned short* __restrict__ hw, const int* __restrict__ row_ptr,
                      const int* __restrict__ col_idx, const float* __restrict__ val,
                      const float* __restrict__ dinv, const float* __restrict__ bias,
                      const float* __restrict__ ln_g, const float* __restrict__ ln_b,
                      unsigned short* __restrict__ out) {
    const int t = blockIdx.x;
    const int tid = threadIdx.x;
    const int e0 = row_ptr[t], e1 = row_ptr[t + 1];
    const ushort4* hw4 = reinterpret_cast<const ushort4*>(hw);
    const float dt = dinv[t];
    const float selfw = dt * dt;
    ushort4 hs = hw4[(size_t)t * 128 + tid];
    float ax = selfw * bf2f(hs.x), ay = selfw * bf2f(hs.y);
    float az = selfw * bf2f(hs.z), aw = selfw * bf2f(hs.w);

    __shared__ int   sh_s[128];
    __shared__ float sh_v[128];
    for (int base = e0; base < e1; base += 128) {
        int cnt = min(128, e1 - base);
        if (tid < cnt) { sh_s[tid] = col_idx[base + tid]; sh_v[tid] = val[base + tid]; }
        __syncthreads();
        for (int j = 0; j < cnt; j++) {
            float w = sh_v[j];
            ushort4 hv = hw4[(size_t)sh_s[j] * 128 + tid];
            ax += w * bf2f(hv.x); ay += w * bf2f(hv.y);
            az += w * bf2f(hv.z); aw += w * bf2f(hv.w);
        }
        __syncthreads();
    }
    int c4 = tid << 2;
    float4 bb = *reinterpret_cast<const float4*>(&bias[c4]);
    ax = fmaxf(ax + bb.x, 0.f); ay = fmaxf(ay + bb.y, 0.f);
    az = fmaxf(az + bb.z, 0.f); aw = fmaxf(aw + bb.w, 0.f);
    __shared__ float redA[2], redB[2];
    float wsum = waveReduceSum(ax + ay + az + aw);
    if ((tid & 63) == 0) redA[tid >> 6] = wsum;
    __syncthreads();
    float mu = (redA[0] + redA[1]) * (1.0f / C);
    float dx = ax - mu, dy = ay - mu, dz = az - mu, dw = aw - mu;
    float wsq = waveReduceSum(dx * dx + dy * dy + dz * dz + dw * dw);
    if ((tid & 63) == 0) redB[tid >> 6] = wsq;
    __syncthreads();
    float rstd = rsqrtf((redB[0] + redB[1]) * (1.0f / C) + LN_EPS);
    float4 g = *reinterpret_cast<const float4*>(&ln_g[c4]);
    float4 b = *reinterpret_cast<const float4*>(&ln_b[c4]);
    ushort4 o = { f2bf(dx * rstd * g.x + b.x), f2bf(dy * rstd * g.y + b.y),
                  f2bf(dz * rstd * g.z + b.z), f2bf(dw * rstd * g.w + b.w) };
    reinterpret_cast<ushort4*>(out)[(size_t)t * 128 + tid] = o;
}

// ---------------- pooling + final LN + head ----------------

__global__ void k_pool1(const unsigned short* __restrict__ h, float* __restrict__ pmax) {
    int g = blockIdx.x, chunk = blockIdx.y;
    int c = threadIdx.x;  // 512
    int r0 = g * V_NODES + chunk * 128;
    float m = -1e30f;
#pragma unroll 4
    for (int r = 0; r < 128; r++)
        m = fmaxf(m, bf2f(h[(size_t)(r0 + r) * C + c]));
    pmax[((size_t)g * POOL_CHUNKS + chunk) * C + c] = m;
}

__global__ void k_pool2_head(const float* __restrict__ pmax, const float* __restrict__ ln_g,
                             const float* __restrict__ ln_b, const float* __restrict__ hw,
                             const float* __restrict__ hb, float* __restrict__ out) {
    __shared__ float sred[8];
    int g = blockIdx.x;
    int c = threadIdx.x;  // 512
    float m = -1e30f;
#pragma unroll
    for (int j = 0; j < POOL_CHUNKS; j++)
        m = fmaxf(m, pmax[((size_t)g * POOL_CHUNKS + j) * C + c]);
    float total = blockSum512(m, sred);
    float mu = total * (1.0f / C);
    float d = m - mu;
    float var = blockSum512(d * d, sred) * (1.0f / C);
    float rstd = rsqrtf(var + LN_EPS);
    float p = d * rstd * ln_g[c] + ln_b[c];
    float r0 = blockSum512(p * hw[c * NCLS + 0], sred);
    float r1 = blockSum512(p * hw[c * NCLS + 1], sred);
    float r2 = blockSum512(p * hw[c * NCLS + 2], sred);
    if (threadIdx.x == 0) {
        out[g * NCLS + 0] = r0 + hb[0];
        out[g * NCLS + 1] = r1 + hb[1];
        out[g * NCLS + 2] = r2 + hb[2];
    }
}

// ---------------- launch ----------------

extern "C" void kernel_launch(void* const* d_in, const int* in_sizes, int n_in,
                              void* d_out, int out_size, void* d_ws, size_t ws_size,
                              hipStream_t stream) {
    const float* x      = (const float*)d_in[0];
    const float* ew     = (const float*)d_in[1];
    const float* w0     = (const float*)d_in[2];
    const float* b0     = (const float*)d_in[3];
    const float* w1     = (const float*)d_in[4];
    const float* b1     = (const float*)d_in[5];
    const float* w2     = (const float*)d_in[6];
    const float* b2     = (const float*)d_in[7];
    const float* ln_g   = (const float*)d_in[8];
    const float* ln_b   = (const float*)d_in[9];
    const float* head_w = (const float*)d_in[10];
    const float* head_b = (const float*)d_in[11];
    const int*   ei     = (const int*)d_in[12];
    float* out = (float*)d_out;

    char* p = (char*)d_ws;
    auto alloc = [&](size_t bytes) { void* r = p; p += (bytes + 255) & ~255ull; return r; };
    unsigned short* bufA = (unsigned short*)alloc((size_t)NV * C * 2);
    unsigned short* bufB = (unsigned short*)alloc((size_t)NV * C * 2);
    unsigned short* wt1  = (unsigned short*)alloc((size_t)C * C * 2);
    unsigned short* wt2  = (unsigned short*)alloc((size_t)C * C * 2);
    float* s0      = (float*)alloc((size_t)NV * 4);
    float* dinv    = (float*)alloc((size_t)NV * 4);
    int*   counts  = (int*)alloc((size_t)NV * 4);
    int*   row_ptr = (int*)alloc((size_t)(NV + 1) * 4);
    int*   cursor  = (int*)alloc((size_t)NV * 4);
    int*   bsum    = (int*)alloc((size_t)SCAN_BLOCKS * 4);
    int*   col_idx = (int*)alloc((size_t)E_TOT * 4);
    float* val     = (float*)alloc((size_t)E_TOT * 4);
    float* pmax    = (float*)alloc((size_t)N_GRAPH * POOL_CHUNKS * C * 4);

    // graph preprocessing
    k_init<<<NV / 256, 256, 0, stream>>>(dinv, counts);
    k_deg_count<<<E_TOT / 256, 256, 0, stream>>>(ei, ew, dinv, counts);
    k_rsqrt<<<NV / 256, 256, 0, stream>>>(dinv);
    k_scan1<<<SCAN_BLOCKS, 256, 0, stream>>>(counts, row_ptr, bsum);
    k_scan2<<<1, 256, 0, stream>>>(bsum);
    k_scan3<<<SCAN_BLOCKS, 256, 0, stream>>>(row_ptr, bsum, cursor);
    k_fill<<<E_TOT / 256, 256, 0, stream>>>(ei, ew, dinv, cursor, col_idx, val);
    k_wt<<<(2 * C * C) / 256, 256, 0, stream>>>(w1, w2, wt1, wt2);

    // layer 0 (collapsed: scalar agg, then expand+LN)
    k_agg0_scalar<<<NV / 256, 256, 0, stream>>>(x, row_ptr, col_idx, val, dinv, s0);
    k_l0post<<<NV, 128, 0, stream>>>(s0, w0, b0, ln_g, ln_b, bufA);

    // layer 1
    k_gemm_mfma<<<dim3(C / 128, NV / 128), 256, 0, stream>>>(bufA, wt1, bufB);
    k_agg<<<NV, 128, 0, stream>>>(bufB, row_ptr, col_idx, val, dinv, b1, ln_g, ln_b, bufA);

    // layer 2
    k_gemm_mfma<<<dim3(C / 128, NV / 128), 256, 0, stream>>>(bufA, wt2, bufB);
    k_agg<<<NV, 128, 0, stream>>>(bufB, row_ptr, col_idx, val, dinv, b2, ln_g, ln_b, bufA);

    // pooling + head
    k_pool1<<<dim3(N_GRAPH, POOL_CHUNKS), C, 0, stream>>>(bufA, pmax);
    k_pool2_head<<<N_GRAPH, C, 0, stream>>>(pmax, ln_g, ln_b, head_w, head_b, out);
}

// Round 8
// 458.825 us; speedup vs baseline: 2.5102x; 1.0218x over previous
//
#include <hip/hip_runtime.h>
#include <hip/hip_bf16.h>
#include <stdint.h>

#define N_GRAPH 8
#define V_NODES 4608
#define E_PER   73728
#define NV      (N_GRAPH * V_NODES)   // 36864
#define E_TOT   (N_GRAPH * E_PER)     // 589824
#define C       512
#define NCLS    3
#define LN_EPS  1e-5f
#define POOL_CHUNKS 36                // V_NODES / 128
#define SCAN_BLOCKS 144               // NV / 256

typedef __attribute__((ext_vector_type(8))) short short8;
typedef __attribute__((ext_vector_type(4))) float floatx4;
typedef __attribute__((address_space(1))) void v_g;
typedef __attribute__((address_space(3))) void v_l;

// ---------------- helpers ----------------

__device__ inline float waveReduceSum(float v) {
#pragma unroll
    for (int o = 32; o > 0; o >>= 1) v += __shfl_down(v, o, 64);
    return v; // valid on lane 0
}

__device__ inline float blockSum512(float v, volatile float* sred) {
    float s = waveReduceSum(v);
    if ((threadIdx.x & 63) == 0) sred[threadIdx.x >> 6] = s;
    __syncthreads();
    float t = 0.f;
#pragma unroll
    for (int i = 0; i < 8; i++) t += sred[i];
    __syncthreads();
    return t;
}

__device__ inline unsigned short f2bf(float f) {   // RNE
    uint32_t u = __float_as_uint(f);
    u += 0x7fffu + ((u >> 16) & 1u);
    return (unsigned short)(u >> 16);
}
__device__ inline float bf2f(unsigned short b) {
    return __uint_as_float(((uint32_t)b) << 16);
}

// ---------------- graph preprocessing ----------------

__global__ void k_init(float* dinv, int* counts) {
    int i = blockIdx.x * 256 + threadIdx.x;
    if (i < NV) { dinv[i] = 1.0f; counts[i] = 0; }  // 1.0 = self-loop weight
}

__global__ void k_deg_count(const int* __restrict__ ei, const float* __restrict__ ew,
                            float* __restrict__ dinv, int* __restrict__ counts) {
    int e = blockIdx.x * 256 + threadIdx.x;
    if (e >= E_TOT) return;
    int off = (e / E_PER) * V_NODES;
    int t = ei[E_TOT + e] + off;
    atomicAdd(&dinv[t], ew[e]);
    atomicAdd(&counts[t], 1);
}

__global__ void k_rsqrt(float* dinv) {
    int i = blockIdx.x * 256 + threadIdx.x;
    if (i < NV) dinv[i] = rsqrtf(dinv[i]);
}

// ---- multi-block exclusive scan of counts -> row_ptr (3 small kernels) ----

__global__ void k_scan1(const int* __restrict__ counts, int* __restrict__ row_ptr,
                        int* __restrict__ bsum) {
    __shared__ int sh[256];
    const int b = blockIdx.x, tid = threadIdx.x;
    const int idx = b * 256 + tid;
    int v = counts[idx];
    sh[tid] = v;
    __syncthreads();
#pragma unroll
    for (int off = 1; off < 256; off <<= 1) {
        int t = (tid >= off) ? sh[tid - off] : 0;
        __syncthreads();
        sh[tid] += t;
        __syncthreads();
    }
    row_ptr[idx] = sh[tid] - v;            // exclusive within block
    if (tid == 255) bsum[b] = sh[255];     // block total
}

__global__ void k_scan2(int* __restrict__ bsum) {   // 1 block, 256 threads
    __shared__ int sh[256];
    const int tid = threadIdx.x;
    int v = (tid < SCAN_BLOCKS) ? bsum[tid] : 0;
    sh[tid] = v;
    __syncthreads();
#pragma unroll
    for (int off = 1; off < 256; off <<= 1) {
        int t = (tid >= off) ? sh[tid - off] : 0;
        __syncthreads();
        sh[tid] += t;
        __syncthreads();
    }
    if (tid < SCAN_BLOCKS) bsum[tid] = sh[tid] - v;  // exclusive block offsets
}

__global__ void k_scan3(int* __restrict__ row_ptr, const int* __restrict__ bsum,
                        int* __restrict__ cursor) {
    const int b = blockIdx.x, tid = threadIdx.x;
    const int idx = b * 256 + tid;
    int v = row_ptr[idx] + bsum[b];
    row_ptr[idx] = v;
    cursor[idx] = v;
    if (idx == 0) row_ptr[NV] = E_TOT;
}

__global__ void k_fill(const int* __restrict__ ei, const float* __restrict__ ew,
                       const float* __restrict__ dinv, int* __restrict__ cursor,
                       int* __restrict__ col_idx, float* __restrict__ val) {
    int e = blockIdx.x * 256 + threadIdx.x;
    if (e >= E_TOT) return;
    int off = (e / E_PER) * V_NODES;
    int s = ei[e] + off;
    int t = ei[E_TOT + e] + off;
    int pos = atomicAdd(&cursor[t], 1);
    col_idx[pos] = s;
    val[pos] = dinv[s] * ew[e] * dinv[t];
}

// ---------------- weight convert: WT[n][k] = bf16(W[k][n]) for w1,w2 ------

__global__ void k_wt(const float* __restrict__ w1, const float* __restrict__ w2,
                     unsigned short* __restrict__ wt1, unsigned short* __restrict__ wt2) {
    int idx = blockIdx.x * 256 + threadIdx.x;     // 0 .. 2*512*512-1
    int which = idx >> 18;
    int rem = idx & 0x3ffff;
    int n = rem >> 9, k = rem & 511;
    const float* W = which ? w2 : w1;
    unsigned short* WT = which ? wt2 : wt1;
    WT[n * C + k] = f2bf(W[k * C + n]);
}

// ---------------- layer 0 (D_IN=1 collapse): scalar agg then expand -------

__global__ void k_agg0_scalar(const float* __restrict__ x, const int* __restrict__ row_ptr,
                              const int* __restrict__ col_idx, const float* __restrict__ val,
                              const float* __restrict__ dinv, float* __restrict__ s0) {
    int t = blockIdx.x * 256 + threadIdx.x;
    if (t >= NV) return;
    float dt = dinv[t];
    float acc = dt * dt * x[t];
    int e1 = row_ptr[t + 1];
    for (int e = row_ptr[t]; e < e1; e++)
        acc += val[e] * x[col_idx[e]];
    s0[t] = acc;
}

// h0 = bf16( LN( relu(s0*w0 + b0) ) )  — one block (128 thr) per node
__launch_bounds__(128)
__global__ void k_l0post(const float* __restrict__ s0, const float* __restrict__ w0,
                         const float* __restrict__ b0, const float* __restrict__ ln_g,
                         const float* __restrict__ ln_b, unsigned short* __restrict__ out) {
    const int t = blockIdx.x;
    const int tid = threadIdx.x;
    const int c4 = tid << 2;
    float s = s0[t];
    float4 w = *reinterpret_cast<const float4*>(&w0[c4]);
    float4 bb = *reinterpret_cast<const float4*>(&b0[c4]);
    float vx = fmaxf(s * w.x + bb.x, 0.f);
    float vy = fmaxf(s * w.y + bb.y, 0.f);
    float vz = fmaxf(s * w.z + bb.z, 0.f);
    float vw = fmaxf(s * w.w + bb.w, 0.f);
    __shared__ float redA[2], redB[2];
    float wsum = waveReduceSum(vx + vy + vz + vw);
    if ((tid & 63) == 0) redA[tid >> 6] = wsum;
    __syncthreads();
    float mu = (redA[0] + redA[1]) * (1.0f / C);
    float dx = vx - mu, dy = vy - mu, dz = vz - mu, dw = vw - mu;
    float wsq = waveReduceSum(dx * dx + dy * dy + dz * dz + dw * dw);
    if ((tid & 63) == 0) redB[tid >> 6] = wsq;
    __syncthreads();
    float rstd = rsqrtf((redB[0] + redB[1]) * (1.0f / C) + LN_EPS);
    float4 g = *reinterpret_cast<const float4*>(&ln_g[c4]);
    float4 b = *reinterpret_cast<const float4*>(&ln_b[c4]);
    ushort4 o = { f2bf(dx * rstd * g.x + b.x), f2bf(dy * rstd * g.y + b.y),
                  f2bf(dz * rstd * g.z + b.z), f2bf(dw * rstd * g.w + b.w) };
    reinterpret_cast<ushort4*>(out)[(size_t)t * 128 + tid] = o;
}

// ---------------- bf16 MFMA GEMM: Bout[M,N] = A[M,K] @ WT[N,K]^T ----------
// 128x128 tile, 4 waves (2x2 of 64x64), 16x16x32 MFMA, BK=32.
// Grid (M-tiles=288, N-tiles=4): dispatch idx = y*288+x, 288%8==0 -> all 4
// N-blocks sharing an A-panel land on the SAME XCD (A-panel L2 reuse).

__launch_bounds__(256)
__global__ void k_gemm_mfma(const unsigned short* __restrict__ A,
                            const unsigned short* __restrict__ WT,
                            unsigned short* __restrict__ Bout) {
    __shared__ short8 lA[512];
    __shared__ short8 lB[512];
    const int tid = threadIdx.x;
    const int lane = tid & 63;
    const int wave = tid >> 6;
    const int wr = wave >> 1, wc = wave & 1;
    const int l15 = lane & 15, kg = lane >> 4;
    const int m0 = blockIdx.x * 128;      // x = M block (288)
    const int n0 = blockIdx.y * 128;      // y = N block (4)

    floatx4 acc[4][4] = {};

    // staging: slot s = i*256 + tid, s -> (kgs = s>>7, idx = s&127)
    const int s0i = tid, s1i = 256 + tid;
    const int kgs0 = s0i >> 7, idx0 = s0i & 127;
    const int kgs1 = s1i >> 7, idx1 = s1i & 127;
    const unsigned short* gA0 = A + (size_t)(m0 + idx0) * C + kgs0 * 8;
    const unsigned short* gA1 = A + (size_t)(m0 + idx1) * C + kgs1 * 8;
    const unsigned short* gB0 = WT + (size_t)(n0 + idx0) * C + kgs0 * 8;
    const unsigned short* gB1 = WT + (size_t)(n0 + idx1) * C + kgs1 * 8;

    for (int k0 = 0; k0 < C; k0 += 32) {
        __builtin_amdgcn_global_load_lds((v_g*)(gA0 + k0), (v_l*)&lA[s0i], 16, 0, 0);
        __builtin_amdgcn_global_load_lds((v_g*)(gA1 + k0), (v_l*)&lA[s1i], 16, 0, 0);
        __builtin_amdgcn_global_load_lds((v_g*)(gB0 + k0), (v_l*)&lB[s0i], 16, 0, 0);
        __builtin_amdgcn_global_load_lds((v_g*)(gB1 + k0), (v_l*)&lB[s1i], 16, 0, 0);
        asm volatile("s_waitcnt vmcnt(0)" ::: "memory");
        __syncthreads();

        short8 af[4], bf[4];
#pragma unroll
        for (int mi = 0; mi < 4; mi++)
            af[mi] = lA[kg * 128 + wr * 64 + mi * 16 + l15];
#pragma unroll
        for (int ni = 0; ni < 4; ni++)
            bf[ni] = lB[kg * 128 + wc * 64 + ni * 16 + l15];
#pragma unroll
        for (int mi = 0; mi < 4; mi++)
#pragma unroll
            for (int ni = 0; ni < 4; ni++)
                acc[mi][ni] = __builtin_amdgcn_mfma_f32_16x16x32_bf16(
                    af[mi], bf[ni], acc[mi][ni], 0, 0, 0);
        __syncthreads();
    }

    // D layout: col = lane&15, row = (lane>>4)*4 + reg   [m89-verified]
#pragma unroll
    for (int mi = 0; mi < 4; mi++) {
#pragma unroll
        for (int ni = 0; ni < 4; ni++) {
            int n = n0 + wc * 64 + ni * 16 + l15;
#pragma unroll
            for (int r = 0; r < 4; r++) {
                int m = m0 + wr * 64 + mi * 16 + kg * 4 + r;
                Bout[(size_t)m * C + n] = f2bf(acc[mi][ni][r]);
            }
        }
    }
}

// ---------------- aggregate (bf16 gather) + bias + relu + LN --------------
// XCD swizzle: block b -> target (b&7)*V_NODES + (b>>3). Graph g pins to
// XCD g (dispatch maps block i -> XCD i%8): per-XCD gather working set
// drops 37.7 MB -> 4.6 MB (~ L2 size).

__launch_bounds__(128)
__global__ void k_agg(const unsigned short* __restrict__ hw, const int* __restrict__ row_ptr,
                      const int* __restrict__ col_idx, const float* __restrict__ val,
                      const float* __restrict__ dinv, const float* __restrict__ bias,
                      const float* __restrict__ ln_g, const float* __restrict__ ln_b,
                      unsigned short* __restrict__ out) {
    const int b = blockIdx.x;
    const int t = (b & 7) * V_NODES + (b >> 3);
    const int tid = threadIdx.x;
    const int e0 = row_ptr[t], e1 = row_ptr[t + 1];
    const ushort4* hw4 = reinterpret_cast<const ushort4*>(hw);
    const float dt = dinv[t];
    const float selfw = dt * dt;
    ushort4 hs = hw4[(size_t)t * 128 + tid];
    float ax = selfw * bf2f(hs.x), ay = selfw * bf2f(hs.y);
    float az = selfw * bf2f(hs.z), aw = selfw * bf2f(hs.w);

    __shared__ int   sh_s[128];
    __shared__ float sh_v[128];
    for (int base = e0; base < e1; base += 128) {
        int cnt = min(128, e1 - base);
        if (tid < cnt) { sh_s[tid] = col_idx[base + tid]; sh_v[tid] = val[base + tid]; }
        __syncthreads();
        int j = 0;
        for (; j + 2 <= cnt; j += 2) {          // 2-wide: two gathers in flight
            float w0 = sh_v[j], w1 = sh_v[j + 1];
            ushort4 h0 = hw4[(size_t)sh_s[j] * 128 + tid];
            ushort4 h1 = hw4[(size_t)sh_s[j + 1] * 128 + tid];
            ax += w0 * bf2f(h0.x); ay += w0 * bf2f(h0.y);
            az += w0 * bf2f(h0.z); aw += w0 * bf2f(h0.w);
            ax += w1 * bf2f(h1.x); ay += w1 * bf2f(h1.y);
            az += w1 * bf2f(h1.z); aw += w1 * bf2f(h1.w);
        }
        if (j < cnt) {
            float w = sh_v[j];
            ushort4 hv = hw4[(size_t)sh_s[j] * 128 + tid];
            ax += w * bf2f(hv.x); ay += w * bf2f(hv.y);
            az += w * bf2f(hv.z); aw += w * bf2f(hv.w);
        }
        __syncthreads();
    }
    int c4 = tid << 2;
    float4 bb = *reinterpret_cast<const float4*>(&bias[c4]);
    ax = fmaxf(ax + bb.x, 0.f); ay = fmaxf(ay + bb.y, 0.f);
    az = fmaxf(az + bb.z, 0.f); aw = fmaxf(aw + bb.w, 0.f);
    __shared__ float redA[2], redB[2];
    float wsum = waveReduceSum(ax + ay + az + aw);
    if ((tid & 63) == 0) redA[tid >> 6] = wsum;
    __syncthreads();
    float mu = (redA[0] + redA[1]) * (1.0f / C);
    float dx = ax - mu, dy = ay - mu, dz = az - mu, dw = aw - mu;
    float wsq = waveReduceSum(dx * dx + dy * dy + dz * dz + dw * dw);
    if ((tid & 63) == 0) redB[tid >> 6] = wsq;
    __syncthreads();
    float rstd = rsqrtf((redB[0] + redB[1]) * (1.0f / C) + LN_EPS);
    float4 g = *reinterpret_cast<const float4*>(&ln_g[c4]);
    float4 b2 = *reinterpret_cast<const float4*>(&ln_b[c4]);
    ushort4 o = { f2bf(dx * rstd * g.x + b2.x), f2bf(dy * rstd * g.y + b2.y),
                  f2bf(dz * rstd * g.z + b2.z), f2bf(dw * rstd * g.w + b2.w) };
    reinterpret_cast<ushort4*>(out)[(size_t)t * 128 + tid] = o;
}

// ---------------- pooling + final LN + head ----------------

__global__ void k_pool1(const unsigned short* __restrict__ h, float* __restrict__ pmax) {
    int g = blockIdx.x, chunk = blockIdx.y;
    int c = threadIdx.x;  // 512
    int r0 = g * V_NODES + chunk * 128;
    float m = -1e30f;
#pragma unroll 4
    for (int r = 0; r < 128; r++)
        m = fmaxf(m, bf2f(h[(size_t)(r0 + r) * C + c]));
    pmax[((size_t)g * POOL_CHUNKS + chunk) * C + c] = m;
}

__global__ void k_pool2_head(const float* __restrict__ pmax, const float* __restrict__ ln_g,
                             const float* __restrict__ ln_b, const float* __restrict__ hw,
                             const float* __restrict__ hb, float* __restrict__ out) {
    __shared__ float sred[8];
    int g = blockIdx.x;
    int c = threadIdx.x;  // 512
    float m = -1e30f;
#pragma unroll
    for (int j = 0; j < POOL_CHUNKS; j++)
        m = fmaxf(m, pmax[((size_t)g * POOL_CHUNKS + j) * C + c]);
    float total = blockSum512(m, sred);
    float mu = total * (1.0f / C);
    float d = m - mu;
    float var = blockSum512(d * d, sred) * (1.0f / C);
    float rstd = rsqrtf(var + LN_EPS);
    float p = d * rstd * ln_g[c] + ln_b[c];
    float r0 = blockSum512(p * hw[c * NCLS + 0], sred);
    float r1 = blockSum512(p * hw[c * NCLS + 1], sred);
    float r2 = blockSum512(p * hw[c * NCLS + 2], sred);
    if (threadIdx.x == 0) {
        out[g * NCLS + 0] = r0 + hb[0];
        out[g * NCLS + 1] = r1 + hb[1];
        out[g * NCLS + 2] = r2 + hb[2];
    }
}

// ---------------- launch ----------------

extern "C" void kernel_launch(void* const* d_in, const int* in_sizes, int n_in,
                              void* d_out, int out_size, void* d_ws, size_t ws_size,
                              hipStream_t stream) {
    const float* x      = (const float*)d_in[0];
    const float* ew     = (const float*)d_in[1];
    const float* w0     = (const float*)d_in[2];
    const float* b0     = (const float*)d_in[3];
    const float* w1     = (const float*)d_in[4];
    const float* b1     = (const float*)d_in[5];
    const float* w2     = (const float*)d_in[6];
    const float* b2     = (const float*)d_in[7];
    const float* ln_g   = (const float*)d_in[8];
    const float* ln_b   = (const float*)d_in[9];
    const float* head_w = (const float*)d_in[10];
    const float* head_b = (const float*)d_in[11];
    const int*   ei     = (const int*)d_in[12];
    float* out = (float*)d_out;

    char* p = (char*)d_ws;
    auto alloc = [&](size_t bytes) { void* r = p; p += (bytes + 255) & ~255ull; return r; };
    unsigned short* bufA = (unsigned short*)alloc((size_t)NV * C * 2);
    unsigned short* bufB = (unsigned short*)alloc((size_t)NV * C * 2);
    unsigned short* wt1  = (unsigned short*)alloc((size_t)C * C * 2);
    unsigned short* wt2  = (unsigned short*)alloc((size_t)C * C * 2);
    float* s0      = (float*)alloc((size_t)NV * 4);
    float* dinv    = (float*)alloc((size_t)NV * 4);
    int*   counts  = (int*)alloc((size_t)NV * 4);
    int*   row_ptr = (int*)alloc((size_t)(NV + 1) * 4);
    int*   cursor  = (int*)alloc((size_t)NV * 4);
    int*   bsum    = (int*)alloc((size_t)SCAN_BLOCKS * 4);
    int*   col_idx = (int*)alloc((size_t)E_TOT * 4);
    float* val     = (float*)alloc((size_t)E_TOT * 4);
    float* pmax    = (float*)alloc((size_t)N_GRAPH * POOL_CHUNKS * C * 4);

    // graph preprocessing
    k_init<<<NV / 256, 256, 0, stream>>>(dinv, counts);
    k_deg_count<<<E_TOT / 256, 256, 0, stream>>>(ei, ew, dinv, counts);
    k_rsqrt<<<NV / 256, 256, 0, stream>>>(dinv);
    k_scan1<<<SCAN_BLOCKS, 256, 0, stream>>>(counts, row_ptr, bsum);
    k_scan2<<<1, 256, 0, stream>>>(bsum);
    k_scan3<<<SCAN_BLOCKS, 256, 0, stream>>>(row_ptr, bsum, cursor);
    k_fill<<<E_TOT / 256, 256, 0, stream>>>(ei, ew, dinv, cursor, col_idx, val);
    k_wt<<<(2 * C * C) / 256, 256, 0, stream>>>(w1, w2, wt1, wt2);

    // layer 0 (collapsed: scalar agg, then expand+LN)
    k_agg0_scalar<<<NV / 256, 256, 0, stream>>>(x, row_ptr, col_idx, val, dinv, s0);
    k_l0post<<<NV, 128, 0, stream>>>(s0, w0, b0, ln_g, ln_b, bufA);

    // layer 1
    k_gemm_mfma<<<dim3(NV / 128, C / 128), 256, 0, stream>>>(bufA, wt1, bufB);
    k_agg<<<NV, 128, 0, stream>>>(bufB, row_ptr, col_idx, val, dinv, b1, ln_g, ln_b, bufA);

    // layer 2
    k_gemm_mfma<<<dim3(NV / 128, C / 128), 256, 0, stream>>>(bufA, wt2, bufB);
    k_agg<<<NV, 128, 0, stream>>>(bufB, row_ptr, col_idx, val, dinv, b2, ln_g, ln_b, bufA);

    // pooling + head
    k_pool1<<<dim3(N_GRAPH, POOL_CHUNKS), C, 0, stream>>>(bufA, pmax);
    k_pool2_head<<<N_GRAPH, C, 0, stream>>>(pmax, ln_g, ln_b, head_w, head_b, out);
}

// Round 9
// 432.511 us; speedup vs baseline: 2.6630x; 1.0608x over previous
//
#include <hip/hip_runtime.h>
#include <hip/hip_bf16.h>
#include <stdint.h>

#define N_GRAPH 8
#define V_NODES 4608
#define E_PER   73728
#define NV      (N_GRAPH * V_NODES)   // 36864
#define E_TOT   (N_GRAPH * E_PER)     // 589824
#define C       512
#define NCLS    3
#define LN_EPS  1e-5f
#define POOL_CHUNKS 36                // V_NODES / 128
#define SCAN_BLOCKS 144               // NV / 256

typedef __attribute__((ext_vector_type(8))) short short8;
typedef __attribute__((ext_vector_type(4))) float floatx4;
typedef __attribute__((address_space(1))) void v_g;
typedef __attribute__((address_space(3))) void v_l;

// ---------------- helpers ----------------

__device__ inline float waveReduceSum(float v) {
#pragma unroll
    for (int o = 32; o > 0; o >>= 1) v += __shfl_down(v, o, 64);
    return v; // valid on lane 0
}

__device__ inline float waveAllSum(float v) {   // butterfly: all lanes get total
#pragma unroll
    for (int o = 32; o > 0; o >>= 1) v += __shfl_xor(v, o, 64);
    return v;
}

__device__ inline float blockSum512(float v, volatile float* sred) {
    float s = waveReduceSum(v);
    if ((threadIdx.x & 63) == 0) sred[threadIdx.x >> 6] = s;
    __syncthreads();
    float t = 0.f;
#pragma unroll
    for (int i = 0; i < 8; i++) t += sred[i];
    __syncthreads();
    return t;
}

__device__ inline unsigned short f2bf(float f) {   // RNE
    uint32_t u = __float_as_uint(f);
    u += 0x7fffu + ((u >> 16) & 1u);
    return (unsigned short)(u >> 16);
}
__device__ inline float bf2f(unsigned short b) {
    return __uint_as_float(((uint32_t)b) << 16);
}

// ---------------- graph preprocessing ----------------

__global__ void k_init(float* dinv, int* counts) {
    int i = blockIdx.x * 256 + threadIdx.x;
    if (i < NV) { dinv[i] = 1.0f; counts[i] = 0; }  // 1.0 = self-loop weight
}

__global__ void k_deg_count(const int* __restrict__ ei, const float* __restrict__ ew,
                            float* __restrict__ dinv, int* __restrict__ counts) {
    int e = blockIdx.x * 256 + threadIdx.x;
    if (e >= E_TOT) return;
    int off = (e / E_PER) * V_NODES;
    int t = ei[E_TOT + e] + off;
    atomicAdd(&dinv[t], ew[e]);
    atomicAdd(&counts[t], 1);
}

__global__ void k_rsqrt(float* dinv) {
    int i = blockIdx.x * 256 + threadIdx.x;
    if (i < NV) dinv[i] = rsqrtf(dinv[i]);
}

// ---- multi-block exclusive scan of counts -> row_ptr (3 small kernels) ----

__global__ void k_scan1(const int* __restrict__ counts, int* __restrict__ row_ptr,
                        int* __restrict__ bsum) {
    __shared__ int sh[256];
    const int b = blockIdx.x, tid = threadIdx.x;
    const int idx = b * 256 + tid;
    int v = counts[idx];
    sh[tid] = v;
    __syncthreads();
#pragma unroll
    for (int off = 1; off < 256; off <<= 1) {
        int t = (tid >= off) ? sh[tid - off] : 0;
        __syncthreads();
        sh[tid] += t;
        __syncthreads();
    }
    row_ptr[idx] = sh[tid] - v;            // exclusive within block
    if (tid == 255) bsum[b] = sh[255];     // block total
}

__global__ void k_scan2(int* __restrict__ bsum) {   // 1 block, 256 threads
    __shared__ int sh[256];
    const int tid = threadIdx.x;
    int v = (tid < SCAN_BLOCKS) ? bsum[tid] : 0;
    sh[tid] = v;
    __syncthreads();
#pragma unroll
    for (int off = 1; off < 256; off <<= 1) {
        int t = (tid >= off) ? sh[tid - off] : 0;
        __syncthreads();
        sh[tid] += t;
        __syncthreads();
    }
    if (tid < SCAN_BLOCKS) bsum[tid] = sh[tid] - v;  // exclusive block offsets
}

__global__ void k_scan3(int* __restrict__ row_ptr, const int* __restrict__ bsum,
                        int* __restrict__ cursor) {
    const int b = blockIdx.x, tid = threadIdx.x;
    const int idx = b * 256 + tid;
    int v = row_ptr[idx] + bsum[b];
    row_ptr[idx] = v;
    cursor[idx] = v;
    if (idx == 0) row_ptr[NV] = E_TOT;
}

__global__ void k_fill(const int* __restrict__ ei, const float* __restrict__ ew,
                       const float* __restrict__ dinv, int* __restrict__ cursor,
                       int* __restrict__ col_idx, float* __restrict__ val) {
    int e = blockIdx.x * 256 + threadIdx.x;
    if (e >= E_TOT) return;
    int off = (e / E_PER) * V_NODES;
    int s = ei[e] + off;
    int t = ei[E_TOT + e] + off;
    int pos = atomicAdd(&cursor[t], 1);
    col_idx[pos] = s;
    val[pos] = dinv[s] * ew[e] * dinv[t];
}

// ---------------- weight convert: WT[n][k] = bf16(W[k][n]) for w1,w2 ------

__global__ void k_wt(const float* __restrict__ w1, const float* __restrict__ w2,
                     unsigned short* __restrict__ wt1, unsigned short* __restrict__ wt2) {
    int idx = blockIdx.x * 256 + threadIdx.x;     // 0 .. 2*512*512-1
    int which = idx >> 18;
    int rem = idx & 0x3ffff;
    int n = rem >> 9, k = rem & 511;
    const float* W = which ? w2 : w1;
    unsigned short* WT = which ? wt2 : wt1;
    WT[n * C + k] = f2bf(W[k * C + n]);
}

// ---------------- layer 0 (D_IN=1 collapse): scalar agg then expand -------

__global__ void k_agg0_scalar(const float* __restrict__ x, const int* __restrict__ row_ptr,
                              const int* __restrict__ col_idx, const float* __restrict__ val,
                              const float* __restrict__ dinv, float* __restrict__ s0) {
    int t = blockIdx.x * 256 + threadIdx.x;
    if (t >= NV) return;
    float dt = dinv[t];
    float acc = dt * dt * x[t];
    int e1 = row_ptr[t + 1];
    for (int e = row_ptr[t]; e < e1; e++)
        acc += val[e] * x[col_idx[e]];
    s0[t] = acc;
}

// h0 = bf16( LN( relu(s0*w0 + b0) ) )  — one block (128 thr) per node
__launch_bounds__(128)
__global__ void k_l0post(const float* __restrict__ s0, const float* __restrict__ w0,
                         const float* __restrict__ b0, const float* __restrict__ ln_g,
                         const float* __restrict__ ln_b, unsigned short* __restrict__ out) {
    const int t = blockIdx.x;
    const int tid = threadIdx.x;
    const int c4 = tid << 2;
    float s = s0[t];
    float4 w = *reinterpret_cast<const float4*>(&w0[c4]);
    float4 bb = *reinterpret_cast<const float4*>(&b0[c4]);
    float vx = fmaxf(s * w.x + bb.x, 0.f);
    float vy = fmaxf(s * w.y + bb.y, 0.f);
    float vz = fmaxf(s * w.z + bb.z, 0.f);
    float vw = fmaxf(s * w.w + bb.w, 0.f);
    __shared__ float redA[2], redB[2];
    float wsum = waveReduceSum(vx + vy + vz + vw);
    if ((tid & 63) == 0) redA[tid >> 6] = wsum;
    __syncthreads();
    float mu = (redA[0] + redA[1]) * (1.0f / C);
    float dx = vx - mu, dy = vy - mu, dz = vz - mu, dw = vw - mu;
    float wsq = waveReduceSum(dx * dx + dy * dy + dz * dz + dw * dw);
    if ((tid & 63) == 0) redB[tid >> 6] = wsq;
    __syncthreads();
    float rstd = rsqrtf((redB[0] + redB[1]) * (1.0f / C) + LN_EPS);
    float4 g = *reinterpret_cast<const float4*>(&ln_g[c4]);
    float4 b = *reinterpret_cast<const float4*>(&ln_b[c4]);
    ushort4 o = { f2bf(dx * rstd * g.x + b.x), f2bf(dy * rstd * g.y + b.y),
                  f2bf(dz * rstd * g.z + b.z), f2bf(dw * rstd * g.w + b.w) };
    reinterpret_cast<ushort4*>(out)[(size_t)t * 128 + tid] = o;
}

// ---------------- bf16 MFMA GEMM: Bout[M,N] = A[M,K] @ WT[N,K]^T ----------
// 128x128 tile, 4 waves (2x2 of 64x64), 16x16x32 MFMA, BK=32.
// Grid (M-tiles=288, N-tiles=4): dispatch idx = y*288+x, 288%8==0 -> all 4
// N-blocks sharing an A-panel land on the SAME XCD (A-panel L2 reuse).

__launch_bounds__(256)
__global__ void k_gemm_mfma(const unsigned short* __restrict__ A,
                            const unsigned short* __restrict__ WT,
                            unsigned short* __restrict__ Bout) {
    __shared__ short8 lA[512];
    __shared__ short8 lB[512];
    const int tid = threadIdx.x;
    const int lane = tid & 63;
    const int wave = tid >> 6;
    const int wr = wave >> 1, wc = wave & 1;
    const int l15 = lane & 15, kg = lane >> 4;
    const int m0 = blockIdx.x * 128;      // x = M block (288)
    const int n0 = blockIdx.y * 128;      // y = N block (4)

    floatx4 acc[4][4] = {};

    // staging: slot s = i*256 + tid, s -> (kgs = s>>7, idx = s&127)
    const int s0i = tid, s1i = 256 + tid;
    const int kgs0 = s0i >> 7, idx0 = s0i & 127;
    const int kgs1 = s1i >> 7, idx1 = s1i & 127;
    const unsigned short* gA0 = A + (size_t)(m0 + idx0) * C + kgs0 * 8;
    const unsigned short* gA1 = A + (size_t)(m0 + idx1) * C + kgs1 * 8;
    const unsigned short* gB0 = WT + (size_t)(n0 + idx0) * C + kgs0 * 8;
    const unsigned short* gB1 = WT + (size_t)(n0 + idx1) * C + kgs1 * 8;

    for (int k0 = 0; k0 < C; k0 += 32) {
        __builtin_amdgcn_global_load_lds((v_g*)(gA0 + k0), (v_l*)&lA[s0i], 16, 0, 0);
        __builtin_amdgcn_global_load_lds((v_g*)(gA1 + k0), (v_l*)&lA[s1i], 16, 0, 0);
        __builtin_amdgcn_global_load_lds((v_g*)(gB0 + k0), (v_l*)&lB[s0i], 16, 0, 0);
        __builtin_amdgcn_global_load_lds((v_g*)(gB1 + k0), (v_l*)&lB[s1i], 16, 0, 0);
        asm volatile("s_waitcnt vmcnt(0)" ::: "memory");
        __syncthreads();

        short8 af[4], bf[4];
#pragma unroll
        for (int mi = 0; mi < 4; mi++)
            af[mi] = lA[kg * 128 + wr * 64 + mi * 16 + l15];
#pragma unroll
        for (int ni = 0; ni < 4; ni++)
            bf[ni] = lB[kg * 128 + wc * 64 + ni * 16 + l15];
#pragma unroll
        for (int mi = 0; mi < 4; mi++)
#pragma unroll
            for (int ni = 0; ni < 4; ni++)
                acc[mi][ni] = __builtin_amdgcn_mfma_f32_16x16x32_bf16(
                    af[mi], bf[ni], acc[mi][ni], 0, 0, 0);
        __syncthreads();
    }

    // D layout: col = lane&15, row = (lane>>4)*4 + reg   [m89-verified]
#pragma unroll
    for (int mi = 0; mi < 4; mi++) {
#pragma unroll
        for (int ni = 0; ni < 4; ni++) {
            int n = n0 + wc * 64 + ni * 16 + l15;
#pragma unroll
            for (int r = 0; r < 4; r++) {
                int m = m0 + wr * 64 + mi * 16 + kg * 4 + r;
                Bout[(size_t)m * C + n] = f2bf(acc[mi][ni][r]);
            }
        }
    }
}

// ---------------- aggregate: ONE WAVE PER NODE, no barriers ---------------
// 64 lanes x ushort8 (16B) = full 512-ch row per wave. Edge idx/val are
// wave-uniform loads (SMEM path). 4 nodes per 256-thr block; grid 9216%8==0
// keeps graph g -> XCD g pinning (per-XCD gather set 4.6 MB ~ L2).

__launch_bounds__(256)
__global__ void k_agg(const unsigned short* __restrict__ hw, const int* __restrict__ row_ptr,
                      const int* __restrict__ col_idx, const float* __restrict__ val,
                      const float* __restrict__ dinv, const float* __restrict__ bias,
                      const float* __restrict__ ln_g, const float* __restrict__ ln_b,
                      unsigned short* __restrict__ out) {
    const int b = blockIdx.x;
    const int wv = threadIdx.x >> 6;
    const int lane = threadIdx.x & 63;
    const int t = (b & 7) * V_NODES + ((b >> 3) << 2) + wv;   // bijective
    const int e0 = row_ptr[t], e1 = row_ptr[t + 1];
    const short8* hw8 = reinterpret_cast<const short8*>(hw);

    const float dt = dinv[t];
    const float selfw = dt * dt;
    short8 hs = hw8[(size_t)t * 64 + lane];
    float a[8];
#pragma unroll
    for (int i = 0; i < 8; i++) a[i] = selfw * bf2f((unsigned short)hs[i]);

    int e = e0;
    for (; e + 4 <= e1; e += 4) {                 // 4 gathers in flight
        int i0 = col_idx[e], i1 = col_idx[e + 1], i2 = col_idx[e + 2], i3 = col_idx[e + 3];
        float w0 = val[e], w1 = val[e + 1], w2 = val[e + 2], w3 = val[e + 3];
        short8 h0 = hw8[(size_t)i0 * 64 + lane];
        short8 h1 = hw8[(size_t)i1 * 64 + lane];
        short8 h2 = hw8[(size_t)i2 * 64 + lane];
        short8 h3 = hw8[(size_t)i3 * 64 + lane];
#pragma unroll
        for (int i = 0; i < 8; i++) a[i] += w0 * bf2f((unsigned short)h0[i]);
#pragma unroll
        for (int i = 0; i < 8; i++) a[i] += w1 * bf2f((unsigned short)h1[i]);
#pragma unroll
        for (int i = 0; i < 8; i++) a[i] += w2 * bf2f((unsigned short)h2[i]);
#pragma unroll
        for (int i = 0; i < 8; i++) a[i] += w3 * bf2f((unsigned short)h3[i]);
    }
    for (; e < e1; e++) {
        int is = col_idx[e];
        float w = val[e];
        short8 hv = hw8[(size_t)is * 64 + lane];
#pragma unroll
        for (int i = 0; i < 8; i++) a[i] += w * bf2f((unsigned short)hv[i]);
    }

    // bias + relu
    const int c8 = lane << 3;
    float4 bb0 = *reinterpret_cast<const float4*>(&bias[c8]);
    float4 bb1 = *reinterpret_cast<const float4*>(&bias[c8 + 4]);
    a[0] = fmaxf(a[0] + bb0.x, 0.f); a[1] = fmaxf(a[1] + bb0.y, 0.f);
    a[2] = fmaxf(a[2] + bb0.z, 0.f); a[3] = fmaxf(a[3] + bb0.w, 0.f);
    a[4] = fmaxf(a[4] + bb1.x, 0.f); a[5] = fmaxf(a[5] + bb1.y, 0.f);
    a[6] = fmaxf(a[6] + bb1.z, 0.f); a[7] = fmaxf(a[7] + bb1.w, 0.f);

    // layernorm, wave-local (no barriers)
    float s = a[0] + a[1] + a[2] + a[3] + a[4] + a[5] + a[6] + a[7];
    float mu = waveAllSum(s) * (1.0f / C);
    float sq = 0.f;
#pragma unroll
    for (int i = 0; i < 8; i++) { float d = a[i] - mu; sq += d * d; }
    float rstd = rsqrtf(waveAllSum(sq) * (1.0f / C) + LN_EPS);

    float4 g0 = *reinterpret_cast<const float4*>(&ln_g[c8]);
    float4 g1 = *reinterpret_cast<const float4*>(&ln_g[c8 + 4]);
    float4 z0 = *reinterpret_cast<const float4*>(&ln_b[c8]);
    float4 z1 = *reinterpret_cast<const float4*>(&ln_b[c8 + 4]);
    short8 o;
    o[0] = (short)f2bf((a[0] - mu) * rstd * g0.x + z0.x);
    o[1] = (short)f2bf((a[1] - mu) * rstd * g0.y + z0.y);
    o[2] = (short)f2bf((a[2] - mu) * rstd * g0.z + z0.z);
    o[3] = (short)f2bf((a[3] - mu) * rstd * g0.w + z0.w);
    o[4] = (short)f2bf((a[4] - mu) * rstd * g1.x + z1.x);
    o[5] = (short)f2bf((a[5] - mu) * rstd * g1.y + z1.y);
    o[6] = (short)f2bf((a[6] - mu) * rstd * g1.z + z1.z);
    o[7] = (short)f2bf((a[7] - mu) * rstd * g1.w + z1.w);
    reinterpret_cast<short8*>(out)[(size_t)t * 64 + lane] = o;
}

// ---------------- pooling + final LN + head ----------------

__global__ void k_pool1(const unsigned short* __restrict__ h, float* __restrict__ pmax) {
    int g = blockIdx.x, chunk = blockIdx.y;
    int c = threadIdx.x;  // 512
    int r0 = g * V_NODES + chunk * 128;
    float m = -1e30f;
#pragma unroll 4
    for (int r = 0; r < 128; r++)
        m = fmaxf(m, bf2f(h[(size_t)(r0 + r) * C + c]));
    pmax[((size_t)g * POOL_CHUNKS + chunk) * C + c] = m;
}

__global__ void k_pool2_head(const float* __restrict__ pmax, const float* __restrict__ ln_g,
                             const float* __restrict__ ln_b, const float* __restrict__ hw,
                             const float* __restrict__ hb, float* __restrict__ out) {
    __shared__ float sred[8];
    int g = blockIdx.x;
    int c = threadIdx.x;  // 512
    float m = -1e30f;
#pragma unroll
    for (int j = 0; j < POOL_CHUNKS; j++)
        m = fmaxf(m, pmax[((size_t)g * POOL_CHUNKS + j) * C + c]);
    float total = blockSum512(m, sred);
    float mu = total * (1.0f / C);
    float d = m - mu;
    float var = blockSum512(d * d, sred) * (1.0f / C);
    float rstd = rsqrtf(var + LN_EPS);
    float p = d * rstd * ln_g[c] + ln_b[c];
    float r0 = blockSum512(p * hw[c * NCLS + 0], sred);
    float r1 = blockSum512(p * hw[c * NCLS + 1], sred);
    float r2 = blockSum512(p * hw[c * NCLS + 2], sred);
    if (threadIdx.x == 0) {
        out[g * NCLS + 0] = r0 + hb[0];
        out[g * NCLS + 1] = r1 + hb[1];
        out[g * NCLS + 2] = r2 + hb[2];
    }
}

// ---------------- launch ----------------

extern "C" void kernel_launch(void* const* d_in, const int* in_sizes, int n_in,
                              void* d_out, int out_size, void* d_ws, size_t ws_size,
                              hipStream_t stream) {
    const float* x      = (const float*)d_in[0];
    const float* ew     = (const float*)d_in[1];
    const float* w0     = (const float*)d_in[2];
    const float* b0     = (const float*)d_in[3];
    const float* w1     = (const float*)d_in[4];
    const float* b1     = (const float*)d_in[5];
    const float* w2     = (const float*)d_in[6];
    const float* b2     = (const float*)d_in[7];
    const float* ln_g   = (const float*)d_in[8];
    const float* ln_b   = (const float*)d_in[9];
    const float* head_w = (const float*)d_in[10];
    const float* head_b = (const float*)d_in[11];
    const int*   ei     = (const int*)d_in[12];
    float* out = (float*)d_out;

    char* p = (char*)d_ws;
    auto alloc = [&](size_t bytes) { void* r = p; p += (bytes + 255) & ~255ull; return r; };
    unsigned short* bufA = (unsigned short*)alloc((size_t)NV * C * 2);
    unsigned short* bufB = (unsigned short*)alloc((size_t)NV * C * 2);
    unsigned short* wt1  = (unsigned short*)alloc((size_t)C * C * 2);
    unsigned short* wt2  = (unsigned short*)alloc((size_t)C * C * 2);
    float* s0      = (float*)alloc((size_t)NV * 4);
    float* dinv    = (float*)alloc((size_t)NV * 4);
    int*   counts  = (int*)alloc((size_t)NV * 4);
    int*   row_ptr = (int*)alloc((size_t)(NV + 1) * 4);
    int*   cursor  = (int*)alloc((size_t)NV * 4);
    int*   bsum    = (int*)alloc((size_t)SCAN_BLOCKS * 4);
    int*   col_idx = (int*)alloc((size_t)E_TOT * 4);
    float* val     = (float*)alloc((size_t)E_TOT * 4);
    float* pmax    = (float*)alloc((size_t)N_GRAPH * POOL_CHUNKS * C * 4);

    // graph preprocessing
    k_init<<<NV / 256, 256, 0, stream>>>(dinv, counts);
    k_deg_count<<<E_TOT / 256, 256, 0, stream>>>(ei, ew, dinv, counts);
    k_rsqrt<<<NV / 256, 256, 0, stream>>>(dinv);
    k_scan1<<<SCAN_BLOCKS, 256, 0, stream>>>(counts, row_ptr, bsum);
    k_scan2<<<1, 256, 0, stream>>>(bsum);
    k_scan3<<<SCAN_BLOCKS, 256, 0, stream>>>(row_ptr, bsum, cursor);
    k_fill<<<E_TOT / 256, 256, 0, stream>>>(ei, ew, dinv, cursor, col_idx, val);
    k_wt<<<(2 * C * C) / 256, 256, 0, stream>>>(w1, w2, wt1, wt2);

    // layer 0 (collapsed: scalar agg, then expand+LN)
    k_agg0_scalar<<<NV / 256, 256, 0, stream>>>(x, row_ptr, col_idx, val, dinv, s0);
    k_l0post<<<NV, 128, 0, stream>>>(s0, w0, b0, ln_g, ln_b, bufA);

    // layer 1
    k_gemm_mfma<<<dim3(NV / 128, C / 128), 256, 0, stream>>>(bufA, wt1, bufB);
    k_agg<<<NV / 4, 256, 0, stream>>>(bufB, row_ptr, col_idx, val, dinv, b1, ln_g, ln_b, bufA);

    // layer 2
    k_gemm_mfma<<<dim3(NV / 128, C / 128), 256, 0, stream>>>(bufA, wt2, bufB);
    k_agg<<<NV / 4, 256, 0, stream>>>(bufB, row_ptr, col_idx, val, dinv, b2, ln_g, ln_b, bufA);

    // pooling + head
    k_pool1<<<dim3(N_GRAPH, POOL_CHUNKS), C, 0, stream>>>(bufA, pmax);
    k_pool2_head<<<N_GRAPH, C, 0, stream>>>(pmax, ln_g, ln_b, head_w, head_b, out);
}